// Round 15
// baseline (136.487 us; speedup 1.0000x reference)
//
#include <hip/hip_runtime.h>
#include <stdint.h>

#define IN_DIM  4096
#define OUT_DIM 4096
#define BATCH   4096
#define NACT    32

typedef float          f32x4  __attribute__((ext_vector_type(4)));
typedef unsigned short u16x4  __attribute__((ext_vector_type(4)));

// round-to-nearest f32 -> bf16
__device__ inline unsigned short f2bf(float f) {
    unsigned u = __float_as_uint(f);
    u += 0x7FFF + ((u >> 16) & 1);
    return (unsigned short)(u >> 16);
}

// ---------------------------------------------------------------------------
// Fused prep kernel (measured ~27us ~= its 160MB/6.3TB/s roofline).
//   blocks [0, OUT_DIM)              : compress mask+weight -> idx/w tables
//   blocks [OUT_DIM, OUT_DIM+4096)   : transpose x -> xT bf16 [IN_DIM][BATCH]
// ---------------------------------------------------------------------------
__global__ __launch_bounds__(256)
void prep_kernel(const float* __restrict__ weight,
                 const int*   __restrict__ mask,
                 const float* __restrict__ x,
                 int*         __restrict__ idx_tab,
                 float*       __restrict__ w_tab,
                 unsigned short* __restrict__ xT) {
    __shared__ float tile[64][65];        // transpose tile; aliased as scan[]
    int* scan = (int*)&tile[0][0];
    const int t = threadIdx.x;

    if (blockIdx.x < OUT_DIM) {
        // ---- compress: one block per output row ----
        const int o = blockIdx.x;
        const int* mrow = mask + (size_t)o * IN_DIM;
        const int  base = t * 16;

        int m[16];
        const int4* m4 = (const int4*)(mrow + base);
        #pragma unroll
        for (int j = 0; j < 4; ++j) {
            int4 v = m4[j];
            m[j*4+0] = v.x; m[j*4+1] = v.y; m[j*4+2] = v.z; m[j*4+3] = v.w;
        }
        int c = 0;
        #pragma unroll
        for (int j = 0; j < 16; ++j) c += (m[j] != 0);

        scan[t] = c;
        __syncthreads();
        for (int off = 1; off < 256; off <<= 1) {
            int add = (t >= off) ? scan[t - off] : 0;
            __syncthreads();
            scan[t] += add;
            __syncthreads();
        }
        int pos = scan[t] - c;            // exclusive prefix
        for (int j = 0; j < 16; ++j) {
            if (m[j] != 0) {
                int idx = base + j;
                idx_tab[o * NACT + pos] = idx;
                w_tab [o * NACT + pos] = weight[(size_t)o * IN_DIM + idx];
                ++pos;
            }
        }
    } else {
        // ---- transpose + bf16 quantize: 64x64 tile ----
        const int q  = blockIdx.x - OUT_DIM;
        const int bi = q & 63;            // batch tile
        const int bj = q >> 6;            // in-dim tile
        {
            const int c  = (t & 15) * 4;
            const int r0 = t >> 4;
            #pragma unroll
            for (int p = 0; p < 4; ++p) {
                int r = r0 + p * 16;
                float4 v = *(const float4*)(x + (size_t)(bi*64 + r) * IN_DIM + bj*64 + c);
                tile[r][c+0] = v.x; tile[r][c+1] = v.y;
                tile[r][c+2] = v.z; tile[r][c+3] = v.w;
            }
        }
        __syncthreads();
        {
            const int b4 = (t & 15) * 4;
            const int j0 = t >> 4;
            #pragma unroll
            for (int p = 0; p < 4; ++p) {
                int j = j0 + p * 16;
                u16x4 v = { f2bf(tile[b4+0][j]), f2bf(tile[b4+1][j]),
                            f2bf(tile[b4+2][j]), f2bf(tile[b4+3][j]) };
                *(u16x4*)(xT + (size_t)(bj*64 + j) * BATCH + bi*64 + b4) = v;
            }
        }
    }
}

// ---------------------------------------------------------------------------
// Main sparse matmul — r10 memory pattern, halved accumulator pressure.
// Block = 256 threads = 4 waves covering the SAME 256-batch x 16-output
// tile as r10: waves 0-1 compute outputs o0..o0+7, waves 2-3 compute
// o0+8..o0+15; thread = 2 batches x 8 outputs -> 16 acc VGPRs (r10: 32).
// Rationale (r14 counters): VGPR=40 with 32 accs left ~4-8 gathers in
// flight/wave; issue model (512 loads / ~4 inflight x ~400cy) reproduces
// the 64us. Freeing 16 regs lets the compiler hold ~4x more gathers in
// flight. Total wave-load count is unchanged (256/wave x 4 waves).
// Everything proven kept: 2 MB L2-resident slab, SALU row addressing
// (readfirstlane -> saddr), dword = 2 batches/load, nt + two-pass LDS
// restage L[128][17] (full 64B lines), slab-major XCD swizzle.
// Static occupancy: 8 blocks/CU x 4 waves = 32 waves/CU = 100%.
// ---------------------------------------------------------------------------
__global__ __launch_bounds__(256)
void spmm_kernel(const unsigned short* __restrict__ xT,
                 const int*   __restrict__ idx_tab,
                 const float* __restrict__ w_tab,
                 const float* __restrict__ bias,
                 float*       __restrict__ out) {
    const int t   = threadIdx.x;          // 0..255
    const int w2  = t >> 7;               // o-half: 0 -> o0..7, 1 -> o0+8..15
    const int tl  = t & 127;              // batch-pair id 0..127
    const int bid = blockIdx.x;           // 4096 blocks
    const int v    = (bid & 7) * 512 + (bid >> 3);   // bijective XCD swizzle
    const int slab = v >> 8;              // 0..15 (slab-major per XCD)
    const int ot   = v & 255;             // o-tile minor
    const int o0   = ot * 16;
    const int ow   = o0 + w2 * 8;         // this half's first output
    const int b0   = slab * 256;          // slab batch base
    const int bl   = tl * 2;              // batch-local (even)

    const unsigned* xTd = (const unsigned*)xT;     // dword view (2 bf16/dword)
    const int bl2 = (b0 >> 1) + tl;       // this thread's dword column

    float acc0[8], acc1[8];
    #pragma unroll 2
    for (int o = 0; o < 8; ++o) {
        const int*   ip = idx_tab + (size_t)(ow + o) * NACT;   // wave-uniform
        const float* wp = w_tab   + (size_t)(ow + o) * NACT;   // -> s_load
        float a00 = 0.f, a01 = 0.f, a10 = 0.f, a11 = 0.f;
        #pragma unroll
        for (int k = 0; k < NACT; k += 2) {
            int r0 = __builtin_amdgcn_readfirstlane(ip[k]);    // force SGPR
            int r1 = __builtin_amdgcn_readfirstlane(ip[k+1]);
            unsigned u0 = xTd[(size_t)r0 * (BATCH/2) + bl2];   // saddr + voff
            unsigned u1 = xTd[(size_t)r1 * (BATCH/2) + bl2];
            float x00 = __uint_as_float(u0 << 16);          // batch bl
            float x01 = __uint_as_float(u0 & 0xFFFF0000u);  // batch bl+1
            float x10 = __uint_as_float(u1 << 16);
            float x11 = __uint_as_float(u1 & 0xFFFF0000u);
            a00 = fmaf(wp[k],   x00, a00);
            a01 = fmaf(wp[k],   x01, a01);
            a10 = fmaf(wp[k+1], x10, a10);
            a11 = fmaf(wp[k+1], x11, a11);
        }
        const float bo = bias[ow + o];
        acc0[o] = (a00 + a10) - bo;
        acc1[o] = (a01 + a11) - bo;
    }

    // ---- two-pass restage through LDS for full-line nt stores ----
    __shared__ float L[128 * 17];         // 8.7 KB: half-slab at a time
    #pragma unroll
    for (int h = 0; h < 2; ++h) {
        if ((tl >> 6) == h) {             // wave-uniform: this half-slab's rows
            const int r = bl & 127;       // row within half-slab
            #pragma unroll
            for (int o = 0; o < 8; ++o) {
                L[(r + 0) * 17 + w2 * 8 + o] = acc0[o];
                L[(r + 1) * 17 + w2 * 8 + o] = acc1[o];
            }
        }
        __syncthreads();
        #pragma unroll
        for (int p = 0; p < 2; ++p) {
            int s = t + p * 256;          // 0..511 sublines
            int r = s >> 2;               // 0..127
            int c = (s & 3) * 4;          // 16B sub-line
            f32x4 rv = { L[r*17 + c+0], L[r*17 + c+1],
                         L[r*17 + c+2], L[r*17 + c+3] };
            __builtin_nontemporal_store(rv,
                (f32x4*)(out + (size_t)(b0 + h*128 + r) * OUT_DIM + o0 + c));
        }
        __syncthreads();                  // L reused by next pass
    }
}

// ---------------------------------------------------------------------------
// Fallback A (ws >= table only): gathers from x directly (uncoalesced, correct).
// ---------------------------------------------------------------------------
__global__ __launch_bounds__(256)
void spmm_noT_kernel(const float* __restrict__ x,
                     const int*   __restrict__ idx_tab,
                     const float* __restrict__ w_tab,
                     const float* __restrict__ bias,
                     float*       __restrict__ out) {
    const int t   = threadIdx.x;
    const int bid = blockIdx.x;           // 4096 blocks
    const int slab = bid >> 8;
    const int ot   = bid & 255;
    const int o0   = ot * 16;
    const int b    = slab * 256 + t;

    float acc[16];
    #pragma unroll 1
    for (int o = 0; o < 16; ++o) {
        const int*   ip = idx_tab + (size_t)(o0 + o) * NACT;
        const float* wp = w_tab   + (size_t)(o0 + o) * NACT;
        float a = 0.f;
        for (int k = 0; k < NACT; ++k)
            a = fmaf(wp[k], x[(size_t)b * IN_DIM + ip[k]], a);
        acc[o] = a - bias[o0 + o];
    }
    float* op = out + (size_t)b * OUT_DIM + o0;
    #pragma unroll
    for (int q = 0; q < 4; ++q) {
        float4 r; r.x = acc[q*4+0]; r.y = acc[q*4+1];
                  r.z = acc[q*4+2]; r.w = acc[q*4+3];
        *(float4*)(op + q*4) = r;
    }
}

// ---------------------------------------------------------------------------
// Fallback B (tiny ws): block per output row; inline compress into LDS.
// ---------------------------------------------------------------------------
__global__ __launch_bounds__(256)
void naive_kernel(const float* __restrict__ x,
                  const float* __restrict__ weight,
                  const float* __restrict__ bias,
                  const int*   __restrict__ mask,
                  float*       __restrict__ out) {
    const int o = blockIdx.x;
    const int t = threadIdx.x;
    __shared__ int   scan[256];
    __shared__ int   sidx[NACT];
    __shared__ float sw[NACT];

    const int* mrow = mask + (size_t)o * IN_DIM;
    const int  base = t * 16;
    int c = 0;
    #pragma unroll
    for (int j = 0; j < 16; ++j) c += (mrow[base + j] != 0);
    scan[t] = c;
    __syncthreads();
    for (int off = 1; off < 256; off <<= 1) {
        int add = (t >= off) ? scan[t - off] : 0;
        __syncthreads();
        scan[t] += add;
        __syncthreads();
    }
    int pos = scan[t] - c;
    for (int j = 0; j < 16; ++j) {
        if (mrow[base + j] != 0) {
            sidx[pos] = base + j;
            sw[pos]   = weight[(size_t)o * IN_DIM + base + j];
            ++pos;
        }
    }
    __syncthreads();
    const float bo = bias[o];
    for (int b = t; b < BATCH; b += 256) {
        float a = 0.f;
        #pragma unroll
        for (int k = 0; k < NACT; ++k)
            a = fmaf(sw[k], x[(size_t)b * IN_DIM + sidx[k]], a);
        out[(size_t)b * OUT_DIM + o] = a - bo;
    }
}

// ---------------------------------------------------------------------------
extern "C" void kernel_launch(void* const* d_in, const int* in_sizes, int n_in,
                              void* d_out, int out_size, void* d_ws, size_t ws_size,
                              hipStream_t stream) {
    const float* x      = (const float*)d_in[0];
    const float* weight = (const float*)d_in[1];
    const float* bias   = (const float*)d_in[2];
    const int*   mask   = (const int*)  d_in[3];
    float* out = (float*)d_out;

    const size_t TAB_BYTES  = (size_t)OUT_DIM * NACT * (sizeof(int) + sizeof(float)); // 1 MB
    const size_t XT_BYTES   = (size_t)IN_DIM * BATCH * sizeof(unsigned short);        // 32 MB
    const size_t NEED_FULL  = TAB_BYTES + XT_BYTES;

    if (ws_size >= NEED_FULL) {
        int*   idx_tab = (int*)d_ws;
        float* w_tab   = (float*)((char*)d_ws + (size_t)OUT_DIM * NACT * sizeof(int));
        unsigned short* xT = (unsigned short*)((char*)d_ws + TAB_BYTES);

        prep_kernel<<<OUT_DIM + (BATCH/64)*(IN_DIM/64), 256, 0, stream>>>(
            weight, mask, x, idx_tab, w_tab, xT);
        spmm_kernel<<<4096, 256, 0, stream>>>(xT, idx_tab, w_tab, bias, out);
    } else if (ws_size >= TAB_BYTES) {
        int*   idx_tab = (int*)d_ws;
        float* w_tab   = (float*)((char*)d_ws + (size_t)OUT_DIM * NACT * sizeof(int));
        prep_kernel<<<OUT_DIM, 256, 0, stream>>>(
            weight, mask, x, idx_tab, w_tab, (unsigned short*)nullptr);
        spmm_noT_kernel<<<4096, 256, 0, stream>>>(x, idx_tab, w_tab, bias, out);
    } else {
        naive_kernel<<<OUT_DIM, 256, 0, stream>>>(x, weight, bias, mask, out);
    }
}

// Round 16
// 91.407 us; speedup vs baseline: 1.4932x; 1.4932x over previous
//
#include <hip/hip_runtime.h>
#include <stdint.h>

#define IN_DIM  4096
#define OUT_DIM 4096
#define BATCH   4096
#define NACT    32

typedef float          f32x4  __attribute__((ext_vector_type(4)));
typedef unsigned short u16x4  __attribute__((ext_vector_type(4)));

// round-to-nearest f32 -> bf16
__device__ inline unsigned short f2bf(float f) {
    unsigned u = __float_as_uint(f);
    u += 0x7FFF + ((u >> 16) & 1);
    return (unsigned short)(u >> 16);
}

// ---------------------------------------------------------------------------
// Fused prep kernel (measured ~27us ~= its 160MB/6.3TB/s roofline).
//   blocks [0, OUT_DIM)              : compress mask+weight -> idx/w tables
//   blocks [OUT_DIM, OUT_DIM+4096)   : transpose x -> xT bf16 [IN_DIM][BATCH]
// ---------------------------------------------------------------------------
__global__ __launch_bounds__(256)
void prep_kernel(const float* __restrict__ weight,
                 const int*   __restrict__ mask,
                 const float* __restrict__ x,
                 int*         __restrict__ idx_tab,
                 float*       __restrict__ w_tab,
                 unsigned short* __restrict__ xT) {
    __shared__ float tile[64][65];        // transpose tile; aliased as scan[]
    int* scan = (int*)&tile[0][0];
    const int t = threadIdx.x;

    if (blockIdx.x < OUT_DIM) {
        // ---- compress: one block per output row ----
        const int o = blockIdx.x;
        const int* mrow = mask + (size_t)o * IN_DIM;
        const int  base = t * 16;

        int m[16];
        const int4* m4 = (const int4*)(mrow + base);
        #pragma unroll
        for (int j = 0; j < 4; ++j) {
            int4 v = m4[j];
            m[j*4+0] = v.x; m[j*4+1] = v.y; m[j*4+2] = v.z; m[j*4+3] = v.w;
        }
        int c = 0;
        #pragma unroll
        for (int j = 0; j < 16; ++j) c += (m[j] != 0);

        scan[t] = c;
        __syncthreads();
        for (int off = 1; off < 256; off <<= 1) {
            int add = (t >= off) ? scan[t - off] : 0;
            __syncthreads();
            scan[t] += add;
            __syncthreads();
        }
        int pos = scan[t] - c;            // exclusive prefix
        for (int j = 0; j < 16; ++j) {
            if (m[j] != 0) {
                int idx = base + j;
                idx_tab[o * NACT + pos] = idx;
                w_tab [o * NACT + pos] = weight[(size_t)o * IN_DIM + idx];
                ++pos;
            }
        }
    } else {
        // ---- transpose + bf16 quantize: 64x64 tile ----
        const int q  = blockIdx.x - OUT_DIM;
        const int bi = q & 63;            // batch tile
        const int bj = q >> 6;            // in-dim tile
        {
            const int c  = (t & 15) * 4;
            const int r0 = t >> 4;
            #pragma unroll
            for (int p = 0; p < 4; ++p) {
                int r = r0 + p * 16;
                float4 v = *(const float4*)(x + (size_t)(bi*64 + r) * IN_DIM + bj*64 + c);
                tile[r][c+0] = v.x; tile[r][c+1] = v.y;
                tile[r][c+2] = v.z; tile[r][c+3] = v.w;
            }
        }
        __syncthreads();
        {
            const int b4 = (t & 15) * 4;
            const int j0 = t >> 4;
            #pragma unroll
            for (int p = 0; p < 4; ++p) {
                int j = j0 + p * 16;
                u16x4 v = { f2bf(tile[b4+0][j]), f2bf(tile[b4+1][j]),
                            f2bf(tile[b4+2][j]), f2bf(tile[b4+3][j]) };
                *(u16x4*)(xT + (size_t)(bj*64 + j) * BATCH + bi*64 + b4) = v;
            }
        }
    }
}

// ---------------------------------------------------------------------------
// Main sparse matmul (r10 structure — session best, 64us spmm).
// Block = 128 threads; thread t = batches (2t, 2t+1) x 16 outputs.
// Slab = 256 batches x 4096 rows x 2B = 2 MB (L2-resident; FETCH ~=
// compulsory; plain stores re-pollute (r9) -> keep nt + restage).
// Gathers: uniform-row-base addressing — row = readfirstlane(ip[k]) keeps
// the row offset in SGPRs, so each gather is s_lshl/s_add (SALU) +
// global_load_dword with per-lane voffset; dword = 2 batches per load.
// Store: TWO-PASS restage through L[128][17] (8.7 KB) -> LDS does not cap
// occupancy; lanes emit full 64B lines as f32x4 nt stores (nt keeps the
// write stream out of L2; full lines avoid partial-line amplification).
// Grid = 16 slabs x 256 o-tiles; swizzle: each XCD sweeps o-tiles slab-major.
// Bracketing: r9 (plain stores), r11 (4 batches/thread), r12 (SGPR-packed
// tables), r13 (global_load_lds pipeline), r15 (4-wave/8-acc, 63% occ) ALL
// regressed or tied -> bound by L2 random-gather service rate (~17 TB/s
// effective, ~half the streaming ubench; saturation signature: more waves
// in flight made it slower).
// ---------------------------------------------------------------------------
__global__ __launch_bounds__(128)
void spmm_kernel(const unsigned short* __restrict__ xT,
                 const int*   __restrict__ idx_tab,
                 const float* __restrict__ w_tab,
                 const float* __restrict__ bias,
                 float*       __restrict__ out) {
    const int t   = threadIdx.x;          // 0..127
    const int bid = blockIdx.x;           // 4096 blocks
    const int v    = (bid & 7) * 512 + (bid >> 3);   // bijective XCD swizzle
    const int slab = v >> 8;              // 0..15 (slab-major per XCD)
    const int ot   = v & 255;             // o-tile minor
    const int o0   = ot * 16;
    const int b0   = slab * 256;          // slab batch base
    const int bl   = t * 2;               // batch-local (even)

    const unsigned* xTd = (const unsigned*)xT;     // dword view (2 bf16/dword)
    const int bl2 = (b0 >> 1) + t;        // this thread's dword column

    float acc0[16], acc1[16];
    #pragma unroll 2
    for (int o = 0; o < 16; ++o) {
        const int*   ip = idx_tab + (size_t)(o0 + o) * NACT;   // wave-uniform
        const float* wp = w_tab   + (size_t)(o0 + o) * NACT;   // -> s_load
        float a00 = 0.f, a01 = 0.f, a10 = 0.f, a11 = 0.f;
        #pragma unroll
        for (int k = 0; k < NACT; k += 2) {
            int r0 = __builtin_amdgcn_readfirstlane(ip[k]);    // force SGPR
            int r1 = __builtin_amdgcn_readfirstlane(ip[k+1]);
            unsigned u0 = xTd[(size_t)r0 * (BATCH/2) + bl2];   // saddr + voff
            unsigned u1 = xTd[(size_t)r1 * (BATCH/2) + bl2];
            float x00 = __uint_as_float(u0 << 16);          // batch bl
            float x01 = __uint_as_float(u0 & 0xFFFF0000u);  // batch bl+1
            float x10 = __uint_as_float(u1 << 16);
            float x11 = __uint_as_float(u1 & 0xFFFF0000u);
            a00 = fmaf(wp[k],   x00, a00);
            a01 = fmaf(wp[k],   x01, a01);
            a10 = fmaf(wp[k+1], x10, a10);
            a11 = fmaf(wp[k+1], x11, a11);
        }
        const float bo = bias[o0 + o];
        acc0[o] = (a00 + a10) - bo;
        acc1[o] = (a01 + a11) - bo;
    }

    // ---- two-pass restage through LDS for full-line nt stores ----
    __shared__ float L[128 * 17];         // 8.7 KB: half-slab at a time
    #pragma unroll
    for (int h = 0; h < 2; ++h) {
        if ((t >> 6) == h) {              // wave-uniform branch
            const int r = bl & 127;       // row within half-slab
            #pragma unroll
            for (int o = 0; o < 16; ++o) {
                L[(r + 0) * 17 + o] = acc0[o];
                L[(r + 1) * 17 + o] = acc1[o];
            }
        }
        __syncthreads();
        const int rr = t >> 2;            // 0..31
        const int c  = (t & 3) * 4;       // 16B sub-line
        #pragma unroll
        for (int p = 0; p < 4; ++p) {
            int r = rr + p * 32;          // 0..127
            f32x4 rv = { L[r*17 + c+0], L[r*17 + c+1],
                         L[r*17 + c+2], L[r*17 + c+3] };
            __builtin_nontemporal_store(rv,
                (f32x4*)(out + (size_t)(b0 + h*128 + r) * OUT_DIM + o0 + c));
        }
        __syncthreads();                  // L reused by next pass
    }
}

// ---------------------------------------------------------------------------
// Fallback A (ws >= table only): gathers from x directly (uncoalesced, correct).
// ---------------------------------------------------------------------------
__global__ __launch_bounds__(256)
void spmm_noT_kernel(const float* __restrict__ x,
                     const int*   __restrict__ idx_tab,
                     const float* __restrict__ w_tab,
                     const float* __restrict__ bias,
                     float*       __restrict__ out) {
    const int t   = threadIdx.x;
    const int bid = blockIdx.x;           // 4096 blocks
    const int slab = bid >> 8;
    const int ot   = bid & 255;
    const int o0   = ot * 16;
    const int b    = slab * 256 + t;

    float acc[16];
    #pragma unroll 1
    for (int o = 0; o < 16; ++o) {
        const int*   ip = idx_tab + (size_t)(o0 + o) * NACT;
        const float* wp = w_tab   + (size_t)(o0 + o) * NACT;
        float a = 0.f;
        for (int k = 0; k < NACT; ++k)
            a = fmaf(wp[k], x[(size_t)b * IN_DIM + ip[k]], a);
        acc[o] = a - bias[o0 + o];
    }
    float* op = out + (size_t)b * OUT_DIM + o0;
    #pragma unroll
    for (int q = 0; q < 4; ++q) {
        float4 r; r.x = acc[q*4+0]; r.y = acc[q*4+1];
                  r.z = acc[q*4+2]; r.w = acc[q*4+3];
        *(float4*)(op + q*4) = r;
    }
}

// ---------------------------------------------------------------------------
// Fallback B (tiny ws): block per output row; inline compress into LDS.
// ---------------------------------------------------------------------------
__global__ __launch_bounds__(256)
void naive_kernel(const float* __restrict__ x,
                  const float* __restrict__ weight,
                  const float* __restrict__ bias,
                  const int*   __restrict__ mask,
                  float*       __restrict__ out) {
    const int o = blockIdx.x;
    const int t = threadIdx.x;
    __shared__ int   scan[256];
    __shared__ int   sidx[NACT];
    __shared__ float sw[NACT];

    const int* mrow = mask + (size_t)o * IN_DIM;
    const int  base = t * 16;
    int c = 0;
    #pragma unroll
    for (int j = 0; j < 16; ++j) c += (mrow[base + j] != 0);
    scan[t] = c;
    __syncthreads();
    for (int off = 1; off < 256; off <<= 1) {
        int add = (t >= off) ? scan[t - off] : 0;
        __syncthreads();
        scan[t] += add;
        __syncthreads();
    }
    int pos = scan[t] - c;
    for (int j = 0; j < 16; ++j) {
        if (mrow[base + j] != 0) {
            sidx[pos] = base + j;
            sw[pos]   = weight[(size_t)o * IN_DIM + base + j];
            ++pos;
        }
    }
    __syncthreads();
    const float bo = bias[o];
    for (int b = t; b < BATCH; b += 256) {
        float a = 0.f;
        #pragma unroll
        for (int k = 0; k < NACT; ++k)
            a = fmaf(sw[k], x[(size_t)b * IN_DIM + sidx[k]], a);
        out[(size_t)b * OUT_DIM + o] = a - bo;
    }
}

// ---------------------------------------------------------------------------
extern "C" void kernel_launch(void* const* d_in, const int* in_sizes, int n_in,
                              void* d_out, int out_size, void* d_ws, size_t ws_size,
                              hipStream_t stream) {
    const float* x      = (const float*)d_in[0];
    const float* weight = (const float*)d_in[1];
    const float* bias   = (const float*)d_in[2];
    const int*   mask   = (const int*)  d_in[3];
    float* out = (float*)d_out;

    const size_t TAB_BYTES  = (size_t)OUT_DIM * NACT * (sizeof(int) + sizeof(float)); // 1 MB
    const size_t XT_BYTES   = (size_t)IN_DIM * BATCH * sizeof(unsigned short);        // 32 MB
    const size_t NEED_FULL  = TAB_BYTES + XT_BYTES;

    if (ws_size >= NEED_FULL) {
        int*   idx_tab = (int*)d_ws;
        float* w_tab   = (float*)((char*)d_ws + (size_t)OUT_DIM * NACT * sizeof(int));
        unsigned short* xT = (unsigned short*)((char*)d_ws + TAB_BYTES);

        prep_kernel<<<OUT_DIM + (BATCH/64)*(IN_DIM/64), 256, 0, stream>>>(
            weight, mask, x, idx_tab, w_tab, xT);
        spmm_kernel<<<4096, 128, 0, stream>>>(xT, idx_tab, w_tab, bias, out);
    } else if (ws_size >= TAB_BYTES) {
        int*   idx_tab = (int*)d_ws;
        float* w_tab   = (float*)((char*)d_ws + (size_t)OUT_DIM * NACT * sizeof(int));
        prep_kernel<<<OUT_DIM, 256, 0, stream>>>(
            weight, mask, x, idx_tab, w_tab, (unsigned short*)nullptr);
        spmm_noT_kernel<<<4096, 256, 0, stream>>>(x, idx_tab, w_tab, bias, out);
    } else {
        naive_kernel<<<OUT_DIM, 256, 0, stream>>>(x, weight, bias, mask, out);
    }
}